// Round 4
// baseline (645.179 us; speedup 1.0000x reference)
//
#include <hip/hip_runtime.h>
#include <hip/hip_cooperative_groups.h>
#include <math.h>

namespace cg = cooperative_groups;

#define BB 16
#define SS 4096
#define DD 1024
#define ND 14
#define THRESH 0.2f

#define CPB 64              // blocks per batch (fused path)
#define ROWS (SS / CPB)     // 64 rows per block
#define GRID (BB * CPB)     // 1024 blocks -> 4 blocks/CU on 256 CUs

typedef float vfloat4 __attribute__((ext_vector_type(4)));

// ---------------------------------------------------------------------------
// Fused cooperative kernel: pool -> (grid sync) -> scores/R (redundant per
// block, kept in registers) -> add. One dispatch, one grid sync.
// z is exactly L3-sized (256 MiB): phase A's read leaves it L3-resident for
// phase C (phase C re-reads the SAME rows this block pooled). out stores are
// nontemporal so the write stream doesn't evict z mid-pass.
// ---------------------------------------------------------------------------
__global__ __launch_bounds__(256, 4) void fused_kernel(
        const float4* __restrict__ z, float4* __restrict__ part,
        vfloat4* __restrict__ out, float* __restrict__ mlc_out,
        const float* __restrict__ M) {
    const int blk = blockIdx.x;
    const int b = blk >> 6;             // blk / CPB
    const int c = blk & (CPB - 1);
    const int t = threadIdx.x;          // float4 lane over D
    const int wave = t >> 6;
    const int lane = t & 63;

    // ---- phase A: partial pool over this block's 64 rows ----
    const float4* zp = z + ((size_t)b * SS + (size_t)c * ROWS) * (DD / 4) + t;
    float4 acc = {0.f, 0.f, 0.f, 0.f};
#pragma unroll 8
    for (int s = 0; s < ROWS; ++s) {
        float4 v = zp[(size_t)s * (DD / 4)];
        acc.x += v.x; acc.y += v.y; acc.z += v.z; acc.w += v.w;
    }
    part[((size_t)b * CPB + c) * (DD / 4) + t] = acc;

    cg::this_grid().sync();

    // ---- phase B: every block computes pooled[b] + scores + R (redundant
    // across the 64 blocks of a batch; ~256 KiB L2/L3 reads each; keeps R
    // in registers and avoids a second grid sync) ----
    __shared__ float pooled[DD];
    __shared__ float sc[ND * 2];
    __shared__ float hat[ND];

    float4 racc = {0.f, 0.f, 0.f, 0.f};
    const float4* pp = part + (size_t)b * CPB * (DD / 4) + t;
    for (int cc = 0; cc < CPB; ++cc) {
        float4 v = pp[(size_t)cc * (DD / 4)];
        racc.x += v.x; racc.y += v.y; racc.z += v.z; racc.w += v.w;
    }
    const float inv = 1.0f / (float)SS;
    ((float4*)pooled)[t] = make_float4(racc.x * inv, racc.y * inv,
                                       racc.z * inv, racc.w * inv);
    __syncthreads();

    // 28 dots: wave w owns idx = w*7 .. w*7+6 (shuffle-only reduce)
    for (int i = 0; i < 7; ++i) {
        const int idx = wave * 7 + i;
        const float* Mrow = M + (size_t)idx * DD;
        float p = 0.f;
#pragma unroll
        for (int k = lane; k < DD; k += 64) p += pooled[k] * Mrow[k];
        for (int off = 32; off > 0; off >>= 1)
            p += __shfl_down(p, off, 64);
        if (lane == 0) sc[idx] = p * (1.0f / 32.0f);   // /sqrt(1024)
    }
    __syncthreads();

    if (t < ND) {
        float a1 = 1.0f / (1.0f + expf(sc[2 * t] - sc[2 * t + 1]));
        if (c == 0) mlc_out[b * ND + t] = a1;          // one writer per batch
        hat[t] = (a1 > THRESH) ? 1.0f : 0.0f;
    }
    __syncthreads();

    float4 r = {0.f, 0.f, 0.f, 0.f};
    const float4* M4 = (const float4*)M;
    for (int n = 0; n < ND; ++n) {
        if (hat[n] != 0.0f) {                          // wave-uniform branch
            float4 m = M4[(size_t)(n * 2 + 1) * (DD / 4) + t];
            r.x += m.x; r.y += m.y; r.z += m.z; r.w += m.w;
        }
    }
    vfloat4 rv; rv.x = r.x; rv.y = r.y; rv.z = r.z; rv.w = r.w;

    // ---- phase C: out = z + R over the SAME rows as phase A ----
    const vfloat4* zz = (const vfloat4*)z;
    const size_t base = ((size_t)b * SS + (size_t)c * ROWS) * (DD / 4) + t;
#pragma unroll 8
    for (int s = 0; s < ROWS; ++s) {
        const size_t idx = base + (size_t)s * (DD / 4);
        vfloat4 v = zz[idx];                           // normal load: L3 hit
        v += rv;
        __builtin_nontemporal_store(v, &out[idx]);     // don't evict z
    }
}

// ===========================================================================
// Fallback 3-kernel path (used only if cooperative launch is unavailable)
// ===========================================================================
__global__ __launch_bounds__(256) void pool_partial(
        const float4* __restrict__ z, float4* __restrict__ part, int rows) {
    const int b = blockIdx.x;
    const int c = blockIdx.y;
    const int t = threadIdx.x;
    const float4* p = z + ((size_t)b * SS + (size_t)c * rows) * (DD / 4) + t;
    float4 acc = {0.f, 0.f, 0.f, 0.f};
#pragma unroll 8
    for (int s = 0; s < rows; ++s) {
        float4 v = p[(size_t)s * (DD / 4)];
        acc.x += v.x; acc.y += v.y; acc.z += v.z; acc.w += v.w;
    }
    part[((size_t)b * gridDim.y + c) * (DD / 4) + t] = acc;
}

__global__ __launch_bounds__(256) void score_kernel(
        const float4* __restrict__ part, const float* __restrict__ M,
        float4* __restrict__ Rout, float* __restrict__ mlc_out, int chunks) {
    const int b = blockIdx.x;
    const int t = threadIdx.x;
    const int wave = t >> 6;
    const int lane = t & 63;

    __shared__ float pooled[DD];
    __shared__ float sc[ND * 2];
    __shared__ float hat[ND];

    float4 acc = {0.f, 0.f, 0.f, 0.f};
    const float4* p = part + (size_t)b * chunks * (DD / 4) + t;
    for (int c = 0; c < chunks; ++c) {
        float4 v = p[(size_t)c * (DD / 4)];
        acc.x += v.x; acc.y += v.y; acc.z += v.z; acc.w += v.w;
    }
    const float inv = 1.0f / (float)SS;
    ((float4*)pooled)[t] = make_float4(acc.x * inv, acc.y * inv,
                                       acc.z * inv, acc.w * inv);
    __syncthreads();

    for (int i = 0; i < 7; ++i) {
        const int idx = wave * 7 + i;
        const float* Mrow = M + (size_t)idx * DD;
        float partial = 0.f;
#pragma unroll
        for (int k = lane; k < DD; k += 64) partial += pooled[k] * Mrow[k];
        for (int off = 32; off > 0; off >>= 1)
            partial += __shfl_down(partial, off, 64);
        if (lane == 0) sc[idx] = partial * (1.0f / 32.0f);
    }
    __syncthreads();

    if (t < ND) {
        float a1 = 1.0f / (1.0f + expf(sc[2 * t] - sc[2 * t + 1]));
        mlc_out[b * ND + t] = a1;
        hat[t] = (a1 > THRESH) ? 1.0f : 0.0f;
    }
    __syncthreads();

    float4 r = {0.f, 0.f, 0.f, 0.f};
    const float4* M4 = (const float4*)M;
    for (int n = 0; n < ND; ++n) {
        if (hat[n] != 0.0f) {
            float4 m = M4[(size_t)(n * 2 + 1) * (DD / 4) + t];
            r.x += m.x; r.y += m.y; r.z += m.z; r.w += m.w;
        }
    }
    Rout[b * (DD / 4) + t] = r;
}

__global__ __launch_bounds__(256) void add_kernel(
        const vfloat4* __restrict__ z, const vfloat4* __restrict__ R,
        vfloat4* __restrict__ out) {
    const int b = blockIdx.x;
    const int c = blockIdx.y;
    const int t = threadIdx.x;
    const vfloat4 r = R[b * (DD / 4) + t];
    const size_t base = ((size_t)b * SS + (size_t)c * 32) * (DD / 4) + t;
#pragma unroll 8
    for (int s = 0; s < 32; ++s) {
        const size_t idx = base + (size_t)s * (DD / 4);
        vfloat4 v = z[idx];
        v += r;
        __builtin_nontemporal_store(v, &out[idx]);
    }
}

extern "C" void kernel_launch(void* const* d_in, const int* in_sizes, int n_in,
                              void* d_out, int out_size, void* d_ws, size_t ws_size,
                              hipStream_t stream) {
    const float* z = (const float*)d_in[0];   // [B][S][D]
    const float* M = (const float*)d_in[1];   // [ND][2][D]
    float* out = (float*)d_out;               // z_out flat, then mlc_probs

    // ws layout: R [B][D] floats (fallback only), then partials
    float* Rws = (float*)d_ws;
    float* part = Rws + (size_t)BB * DD;

    const size_t need_fused = ((size_t)BB * DD + (size_t)BB * CPB * DD) * sizeof(float);

    if (ws_size >= need_fused) {
        const float4* z4 = (const float4*)z;
        float4* part4 = (float4*)part;
        vfloat4* out4 = (vfloat4*)out;
        float* mlc = out + (size_t)BB * SS * DD;
        void* args[] = {(void*)&z4, (void*)&part4, (void*)&out4,
                        (void*)&mlc, (void*)&M};
        hipError_t err = hipLaunchCooperativeKernel(
            (const void*)fused_kernel, dim3(GRID), dim3(256), args, 0, stream);
        if (err == hipSuccess) return;
        // else fall through to 3-kernel path
    }

    size_t avail = ws_size > (size_t)BB * DD * sizeof(float)
                       ? ws_size - (size_t)BB * DD * sizeof(float) : 0;
    int chunks = 128;
    while (chunks > 1 && (size_t)BB * chunks * DD * sizeof(float) > avail)
        chunks >>= 1;
    if (chunks < 1) chunks = 1;
    const int rows = SS / chunks;

    pool_partial<<<dim3(BB, chunks), 256, 0, stream>>>(
        (const float4*)z, (float4*)part, rows);
    score_kernel<<<BB, 256, 0, stream>>>(
        (const float4*)part, M, (float4*)Rws,
        out + (size_t)BB * SS * DD, chunks);
    add_kernel<<<dim3(BB, SS / 32), 256, 0, stream>>>(
        (const vfloat4*)z, (const vfloat4*)Rws, (vfloat4*)out);
}

// Round 6
// 489.464 us; speedup vs baseline: 1.3181x; 1.3181x over previous
//
#include <hip/hip_runtime.h>
#include <math.h>

#define BB 16
#define SS 4096
#define DD 1024
#define ND 14
#define THRESH 0.2f

#define POOL_CH 128          // pool-pass chunks per batch (2048 blocks, 32 rows)
#define ADD_CH 256           // add-pass chunks per batch (4096 blocks, 16 rows)
#define AROWS (SS / ADD_CH)  // 16 rows per add block

typedef float vfloat4 __attribute__((ext_vector_type(4)));

// ---------------------------------------------------------------------------
// Kernel 1: partial mean-pool. grid = (B, POOL_CH), block = 256.
// Normal (cache-allocating) loads on purpose: z (256 MiB) fits Infinity
// Cache, so this pass leaves z L3-resident for the add pass (validated in
// round 4: fused FETCH showed the second z read fully absorbed by L3).
// part layout: [B][POOL_CH][D]
// ---------------------------------------------------------------------------
__global__ __launch_bounds__(256) void pool_partial(
        const float4* __restrict__ z, float4* __restrict__ part) {
    const int b = blockIdx.x;
    const int c = blockIdx.y;
    const int t = threadIdx.x;                      // float4 lane over D
    const int rows = SS / POOL_CH;
    const float4* p = z + ((size_t)b * SS + (size_t)c * rows) * (DD / 4) + t;
    float4 acc = {0.f, 0.f, 0.f, 0.f};
#pragma unroll 8
    for (int s = 0; s < rows; ++s) {
        float4 v = p[(size_t)s * (DD / 4)];
        acc.x += v.x; acc.y += v.y; acc.z += v.z; acc.w += v.w;
    }
    part[((size_t)b * POOL_CH + c) * (DD / 4) + t] = acc;
}

// ---------------------------------------------------------------------------
// Kernel 2: reduce partials -> pooled mean; 28 dots (wave-parallel, float4
// loads); softmax(2)=sigmoid; threshold; R[b][:] = sum of selected M[n][1][:].
// grid = B, block = 256 (4 waves).
// ---------------------------------------------------------------------------
__global__ __launch_bounds__(256) void score_kernel(
        const float4* __restrict__ part, const float* __restrict__ M,
        float4* __restrict__ Rout, float* __restrict__ mlc_out) {
    const int b = blockIdx.x;
    const int t = threadIdx.x;
    const int wave = t >> 6;          // 0..3
    const int lane = t & 63;          // 0..63

    __shared__ float4 pooled4[DD / 4];
    __shared__ float sc[ND * 2];
    __shared__ float hat[ND];

    // reduce partials over chunks
    float4 acc = {0.f, 0.f, 0.f, 0.f};
    const float4* p = part + (size_t)b * POOL_CH * (DD / 4) + t;
    for (int c = 0; c < POOL_CH; ++c) {
        float4 v = p[(size_t)c * (DD / 4)];
        acc.x += v.x; acc.y += v.y; acc.z += v.z; acc.w += v.w;
    }
    const float inv = 1.0f / (float)SS;
    pooled4[t] = make_float4(acc.x * inv, acc.y * inv, acc.z * inv, acc.w * inv);
    __syncthreads();

    // 28 dots: wave w owns idx = w*7 .. w*7+6; per-wave shuffle reduce.
    const float4* M4 = (const float4*)M;
    for (int i = 0; i < 7; ++i) {
        const int idx = wave * 7 + i;
        const float4* Mrow = M4 + (size_t)idx * (DD / 4);
        float partial = 0.f;
#pragma unroll
        for (int k = lane; k < DD / 4; k += 64) {
            float4 a = pooled4[k];
            float4 m = Mrow[k];
            partial += a.x * m.x + a.y * m.y + a.z * m.z + a.w * m.w;
        }
        for (int off = 32; off > 0; off >>= 1)
            partial += __shfl_down(partial, off, 64);
        if (lane == 0) sc[idx] = partial * (1.0f / 32.0f);   // /sqrt(1024)
    }
    __syncthreads();

    if (t < ND) {
        float a1 = 1.0f / (1.0f + expf(sc[2 * t] - sc[2 * t + 1]));  // softmax[...,1]
        mlc_out[b * ND + t] = a1;
        hat[t] = (a1 > THRESH) ? 1.0f : 0.0f;
    }
    __syncthreads();

    // R[b][d] = sum_n hat[n] * M[n][1][d]
    float4 r = {0.f, 0.f, 0.f, 0.f};
    for (int n = 0; n < ND; ++n) {
        if (hat[n] != 0.0f) {   // wave-uniform branch
            float4 m = M4[(size_t)(n * 2 + 1) * (DD / 4) + t];
            r.x += m.x; r.y += m.y; r.z += m.z; r.w += m.w;
        }
    }
    Rout[b * (DD / 4) + t] = r;
}

// ---------------------------------------------------------------------------
// Kernel 3: z_out = z_fused + R[b][:].
// grid = (B, ADD_CH) = 4096 blocks x 16 rows: max resident waves to hide
// store latency. z via NORMAL loads (L3-resident from pool pass); out via
// nontemporal stores so the write stream doesn't evict z mid-pass
// (fill kernel proves write-only streams sustain 6.5 TB/s).
// ---------------------------------------------------------------------------
__global__ __launch_bounds__(256) void add_kernel(
        const vfloat4* __restrict__ z, const vfloat4* __restrict__ R,
        vfloat4* __restrict__ out) {
    const int b = blockIdx.x;
    const int c = blockIdx.y;
    const int t = threadIdx.x;
    const vfloat4 r = R[b * (DD / 4) + t];
    const size_t base = ((size_t)b * SS + (size_t)c * AROWS) * (DD / 4) + t;
#pragma unroll
    for (int s = 0; s < AROWS; ++s) {
        const size_t idx = base + (size_t)s * (DD / 4);
        vfloat4 v = z[idx];                        // normal load: L3 hit
        v += r;
        __builtin_nontemporal_store(v, &out[idx]); // don't evict z
    }
}

extern "C" void kernel_launch(void* const* d_in, const int* in_sizes, int n_in,
                              void* d_out, int out_size, void* d_ws, size_t ws_size,
                              hipStream_t stream) {
    const float* z = (const float*)d_in[0];   // [B][S][D]
    const float* M = (const float*)d_in[1];   // [ND][2][D]
    float* out = (float*)d_out;               // z_out flat, then mlc_probs

    // ws layout: R [B][D] floats, then partials [B][POOL_CH][D] floats
    float* Rws = (float*)d_ws;
    float* part = Rws + (size_t)BB * DD;

    pool_partial<<<dim3(BB, POOL_CH), 256, 0, stream>>>(
        (const float4*)z, (float4*)part);
    score_kernel<<<BB, 256, 0, stream>>>(
        (const float4*)part, M, (float4*)Rws, out + (size_t)BB * SS * DD);
    add_kernel<<<dim3(BB, ADD_CH), 256, 0, stream>>>(
        (const vfloat4*)z, (const vfloat4*)Rws, (vfloat4*)out);
}